// Round 1
// baseline (41.134 us; speedup 1.0000x reference)
//
#include <hip/hip_runtime.h>
#include <hip/hip_bf16.h>

// Problem constants (from reference setup_inputs): emission [B, T, V] float32
#define CTC_B 64
#define CTC_T 8192
#define CTC_V 32
#define BLANK 0

// ---------------------------------------------------------------------------
// Kernel 1: argmax over labels. One thread per (b,t) row of 32 floats (128 B).
// First-occurrence tie-break via strict '>' scan in index order.
// ---------------------------------------------------------------------------
__global__ __launch_bounds__(256) void ctc_argmax_kernel(
    const float* __restrict__ em, unsigned char* __restrict__ idx, int total) {
    int i = blockIdx.x * blockDim.x + threadIdx.x;
    if (i >= total) return;
    const float4* p = reinterpret_cast<const float4*>(em + (size_t)i * CTC_V);
    float best = -__builtin_inff();
    int bi = 0;
#pragma unroll
    for (int j = 0; j < CTC_V / 4; ++j) {
        float4 v = p[j];
        if (v.x > best) { best = v.x; bi = j * 4 + 0; }
        if (v.y > best) { best = v.y; bi = j * 4 + 1; }
        if (v.z > best) { best = v.z; bi = j * 4 + 2; }
        if (v.w > best) { best = v.w; bi = j * 4 + 3; }
    }
    idx[i] = (unsigned char)bi;
}

// ---------------------------------------------------------------------------
// Kernel 2: col_keep[t] = (t==0) || any_b( idx[b,t] != idx[b,t-1] )
// idx array is 512 KiB -> L2-resident; early-exit loop over b.
// ---------------------------------------------------------------------------
__global__ __launch_bounds__(256) void ctc_colkeep_kernel(
    const unsigned char* __restrict__ idx, unsigned char* __restrict__ ck,
    int B, int T) {
    int t = blockIdx.x * blockDim.x + threadIdx.x;
    if (t >= T) return;
    if (t == 0) { ck[0] = 1; return; }
    unsigned char k = 0;
    for (int b = 0; b < B; ++b) {
        if (idx[(size_t)b * T + t] != idx[(size_t)b * T + t - 1]) { k = 1; break; }
    }
    ck[t] = k;
}

// ---------------------------------------------------------------------------
// Kernel 3: per-row stream compaction + tail zero-fill + lens.
// One block (256 threads = 4 waves) per batch row; ballot-based block scan.
// ---------------------------------------------------------------------------
__global__ __launch_bounds__(256) void ctc_compact_kernel(
    const unsigned char* __restrict__ idx, const unsigned char* __restrict__ ck,
    int* __restrict__ btokens, int* __restrict__ lens, int B, int T) {
    int b = blockIdx.x;
    if (b >= B) return;
    const unsigned char* row = idx + (size_t)b * T;
    int* orow = btokens + (size_t)b * T;

    __shared__ int s_base;
    __shared__ int s_wsum[4];  // 256 threads / 64-lane waves = 4
    if (threadIdx.x == 0) s_base = 0;
    __syncthreads();

    const int lane = threadIdx.x & 63;
    const int wid  = threadIdx.x >> 6;
    const unsigned long long lt_mask = (1ULL << lane) - 1ULL;

    for (int base = 0; base < T; base += blockDim.x) {
        int t = base + threadIdx.x;
        unsigned char v = (t < T) ? row[t] : (unsigned char)0;
        unsigned char c = (t < T) ? ck[t]  : (unsigned char)0;
        int k = (c && v != (unsigned char)BLANK) ? 1 : 0;

        unsigned long long bal = __ballot(k);
        int excl   = __popcll(bal & lt_mask);
        int wtotal = __popcll(bal);
        if (lane == 0) s_wsum[wid] = wtotal;
        __syncthreads();

        int woff = 0;
        for (int w = 0; w < wid; ++w) woff += s_wsum[w];
        int pos = s_base + woff + excl;
        if (k) orow[pos] = (int)v;
        __syncthreads();

        if (threadIdx.x == 0)
            s_base += s_wsum[0] + s_wsum[1] + s_wsum[2] + s_wsum[3];
        __syncthreads();
    }

    int count = s_base;
    for (int i = count + threadIdx.x; i < T; i += blockDim.x) orow[i] = BLANK;
    if (threadIdx.x == 0) lens[b] = count;
}

// ---------------------------------------------------------------------------
extern "C" void kernel_launch(void* const* d_in, const int* in_sizes, int n_in,
                              void* d_out, int out_size, void* d_ws, size_t ws_size,
                              hipStream_t stream) {
    const float* emission = (const float*)d_in[0];
    int* out = (int*)d_out;                 // [B*T btokens][B lens], int32
    int* btokens = out;
    int* lens = out + (size_t)CTC_B * CTC_T;

    unsigned char* idx = (unsigned char*)d_ws;                      // B*T bytes
    unsigned char* ck  = idx + (size_t)CTC_B * CTC_T;               // T bytes

    const int total = CTC_B * CTC_T;

    ctc_argmax_kernel<<<(total + 255) / 256, 256, 0, stream>>>(emission, idx, total);
    ctc_colkeep_kernel<<<(CTC_T + 255) / 256, 256, 0, stream>>>(idx, ck, CTC_B, CTC_T);
    ctc_compact_kernel<<<CTC_B, 256, 0, stream>>>(idx, ck, btokens, lens, CTC_B, CTC_T);
}

// Round 2
// 30.164 us; speedup vs baseline: 1.3637x; 1.3637x over previous
//
#include <hip/hip_runtime.h>
#include <hip/hip_bf16.h>

// Problem constants (from reference setup_inputs): emission [B, T, V] float32
#define CTC_B 64
#define CTC_T 8192
#define CTC_V 32
#define BLANK 0

// ---------------------------------------------------------------------------
// Kernel 1: argmax over labels. 8 lanes per (b,t) row; each lane loads one
// float4 -> wave reads a fully contiguous 1 KB segment per load instruction.
// First-occurrence tie-break: strict '>' in-lane (index order), and on the
// cross-lane reduce prefer the smaller index on exact ties.
// ---------------------------------------------------------------------------
__global__ __launch_bounds__(256) void ctc_argmax_kernel(
    const float* __restrict__ em, unsigned char* __restrict__ idx) {
    int tid = blockIdx.x * blockDim.x + threadIdx.x;   // 8 threads per row
    int row = tid >> 3;
    int sub = tid & 7;
    float4 v = reinterpret_cast<const float4*>(em)[(size_t)row * 8 + sub];

    float best = v.x; int bi = 0;
    if (v.y > best) { best = v.y; bi = 1; }
    if (v.z > best) { best = v.z; bi = 2; }
    if (v.w > best) { best = v.w; bi = 3; }
    bi += sub * 4;

    // reduce across the 8-lane group (xor masks 1,2,4 stay in-group)
#pragma unroll
    for (int m = 1; m < 8; m <<= 1) {
        float ob = __shfl_xor(best, m, 64);
        int   oi = __shfl_xor(bi,   m, 64);
        if (ob > best || (ob == best && oi < bi)) { best = ob; bi = oi; }
    }
    if (sub == 0) idx[row] = (unsigned char)bi;   // 8 consecutive bytes/wave
}

// ---------------------------------------------------------------------------
// Kernel 2 (fused colkeep + compact): one block of 1024 threads per batch row.
// col_keep[t] computed inline (early-exit scan over b; idx is L2/L3-resident).
// 8 tiles, ONE barrier per tile: double-buffered wave sums + every thread
// redundantly computes the identical block total, so `base` lives in a
// register replicated across all threads.
// ---------------------------------------------------------------------------
__global__ __launch_bounds__(1024) void ctc_compact_kernel(
    const unsigned char* __restrict__ idx,
    int* __restrict__ btokens, int* __restrict__ lens, int B, int T) {
    int b = blockIdx.x;
    const unsigned char* row = idx + (size_t)b * T;
    int* orow = btokens + (size_t)b * T;

    __shared__ int s_wsum[2][16];   // [parity][wave]
    const int lane = threadIdx.x & 63;
    const int wid  = threadIdx.x >> 6;
    const int nw   = blockDim.x >> 6;           // 16 waves
    const unsigned long long lt = (1ULL << lane) - 1ULL;

    int base = 0;
    int parity = 0;
    for (int tile = 0; tile < T; tile += blockDim.x, parity ^= 1) {
        int t = tile + threadIdx.x;             // T % blockDim == 0
        unsigned char v = row[t];

        int ckeep;
        if (t == 0) {
            ckeep = 1;
        } else {
            ckeep = 0;
            for (int bb = 0; bb < B; ++bb) {
                if (idx[(size_t)bb * T + t] != idx[(size_t)bb * T + t - 1]) {
                    ckeep = 1; break;
                }
            }
        }
        int k = (ckeep && v != (unsigned char)BLANK) ? 1 : 0;

        unsigned long long bal = __ballot(k);
        if (lane == 0) s_wsum[parity][wid] = __popcll(bal);
        __syncthreads();

        int woff = 0, total = 0;
#pragma unroll
        for (int w = 0; w < 16; ++w) {
            int c = s_wsum[parity][w];
            total += (w < nw) ? c : 0;
            if (w < wid) woff += c;
        }
        if (k) orow[base + woff + __popcll(bal & lt)] = (int)v;
        base += total;
        // next tile writes the other parity buffer; the barrier above gates
        // same-parity reuse two tiles apart -> one barrier per tile is safe.
    }

    for (int i = base + threadIdx.x; i < T; i += blockDim.x) orow[i] = BLANK;
    if (threadIdx.x == 0) lens[b] = base;
}

// ---------------------------------------------------------------------------
extern "C" void kernel_launch(void* const* d_in, const int* in_sizes, int n_in,
                              void* d_out, int out_size, void* d_ws, size_t ws_size,
                              hipStream_t stream) {
    const float* emission = (const float*)d_in[0];
    int* out = (int*)d_out;                 // [B*T btokens][B lens], int32
    int* btokens = out;
    int* lens = out + (size_t)CTC_B * CTC_T;

    unsigned char* idx = (unsigned char*)d_ws;   // B*T bytes

    const int total_threads = CTC_B * CTC_T * 8; // 8 lanes per row
    ctc_argmax_kernel<<<total_threads / 256, 256, 0, stream>>>(emission, idx);
    ctc_compact_kernel<<<CTC_B, 1024, 0, stream>>>(idx, btokens, lens, CTC_B, CTC_T);
}

// Round 3
// 23.490 us; speedup vs baseline: 1.7511x; 1.2841x over previous
//
#include <hip/hip_runtime.h>
#include <hip/hip_bf16.h>

// Problem constants (from reference setup_inputs): emission [B, T, V] float32
#define CTC_B 64
#define CTC_T 8192
#define CTC_V 32
#define BLANK 0

// ---------------------------------------------------------------------------
// Kernel 1: argmax over labels. 8 lanes per (b,t) row; each lane loads one
// float4 -> wave reads a fully contiguous 1 KB segment per load instruction.
// First-occurrence tie-break: strict '>' in-lane (index order), and on the
// cross-lane reduce prefer the smaller index on exact ties.
// ---------------------------------------------------------------------------
__global__ __launch_bounds__(256) void ctc_argmax_kernel(
    const float* __restrict__ em, unsigned char* __restrict__ idx) {
    int tid = blockIdx.x * blockDim.x + threadIdx.x;   // 8 threads per row
    int row = tid >> 3;
    int sub = tid & 7;
    float4 v = reinterpret_cast<const float4*>(em)[(size_t)row * 8 + sub];

    float best = v.x; int bi = 0;
    if (v.y > best) { best = v.y; bi = 1; }
    if (v.z > best) { best = v.z; bi = 2; }
    if (v.w > best) { best = v.w; bi = 3; }
    bi += sub * 4;

    // reduce across the 8-lane group (xor masks 1,2,4 stay in-group)
#pragma unroll
    for (int m = 1; m < 8; m <<= 1) {
        float ob = __shfl_xor(best, m, 64);
        int   oi = __shfl_xor(bi,   m, 64);
        if (ob > best || (ob == best && oi < bi)) { best = ob; bi = oi; }
    }
    if (sub == 0) idx[row] = (unsigned char)bi;   // 8 consecutive bytes/wave
}

// ---------------------------------------------------------------------------
// SWAR: high bit of each byte set iff that byte of x is nonzero.
// ---------------------------------------------------------------------------
__device__ __forceinline__ unsigned long long nzmask(unsigned long long x) {
    return (x | ((x & 0x7f7f7f7f7f7f7f7fULL) + 0x7f7f7f7f7f7f7f7fULL))
           & 0x8080808080808080ULL;
}

// ---------------------------------------------------------------------------
// Kernel 2 (fused colkeep + compact): one block of 1024 threads per batch
// row; each thread owns 8 CONSECUTIVE columns (one u64 byte-vector). Single
// pass, single barrier:
//   colkeep: SWAR compare of column t vs t-1 for batch rows 0,1 branchless,
//            rare loop over rows 2..63 only while some byte is undecided.
//   scan:    per-thread popcount -> wave shfl_up scan -> 16-int LDS -> barrier
//   scatter: <=8 consecutive int stores per thread + tail zero-fill.
// ---------------------------------------------------------------------------
__global__ __launch_bounds__(1024) void ctc_compact_kernel(
    const unsigned char* __restrict__ idx,
    int* __restrict__ btokens, int* __restrict__ lens) {
    const int b   = blockIdx.x;
    const int tid = threadIdx.x;
    const int t8  = tid * 8;                     // first column this thread owns
    const unsigned char* row = idx + (size_t)b * CTC_T;
    int* orow = btokens + (size_t)b * CTC_T;

    __shared__ int s_wsum[16];
    const int lane = tid & 63;
    const int wid  = tid >> 6;

    // --- load own 8 values + boundary byte, and dedup rows 0,1 ---
    const unsigned long long xv = *reinterpret_cast<const unsigned long long*>(row + t8);
    const unsigned char* r0 = idx;               // batch row 0
    const unsigned char* r1 = idx + CTC_T;       // batch row 1
    unsigned long long x0 = *reinterpret_cast<const unsigned long long*>(r0 + t8);
    unsigned long long x1 = *reinterpret_cast<const unsigned long long*>(r1 + t8);
    unsigned char p0 = (t8 == 0) ? (unsigned char)0 : r0[t8 - 1];
    unsigned char p1 = (t8 == 0) ? (unsigned char)0 : r1[t8 - 1];

    // colkeep high-bit mask: byte j <-> column t8+j ; prev column = byte j-1
    unsigned long long hk = nzmask(x0 ^ ((x0 << 8) | (unsigned long long)p0))
                          | nzmask(x1 ^ ((x1 << 8) | (unsigned long long)p1));
    if (t8 == 0) hk |= 0x80ULL;                  // col_keep[0] = 1 always

    unsigned long long und = ~hk & 0x8080808080808080ULL;
    for (int bb = 2; bb < CTC_B && und; ++bb) {
        const unsigned char* rb = idx + (size_t)bb * CTC_T;
        unsigned long long xb = *reinterpret_cast<const unsigned long long*>(rb + t8);
        unsigned char pb = (t8 == 0) ? (unsigned char)0 : rb[t8 - 1];
        hk |= nzmask(xb ^ ((xb << 8) | (unsigned long long)pb));
        und = ~hk & 0x8080808080808080ULL;
    }

    // keep = col_keep & (value != BLANK)   (BLANK==0 -> nonzero byte)
    const unsigned long long keep_hi = hk & nzmask(xv);
    const int c = __popcll(keep_hi);

    // --- block exclusive scan of per-thread counts ---
    int scan = c;
#pragma unroll
    for (int m = 1; m < 64; m <<= 1) {
        int o = __shfl_up(scan, m, 64);
        if (lane >= m) scan += o;
    }
    if (lane == 63) s_wsum[wid] = scan;          // wave total (inclusive of last)
    __syncthreads();

    int woff = 0, total = 0;
#pragma unroll
    for (int w = 0; w < 16; ++w) {
        int x = s_wsum[w];
        if (w < wid) woff += x;
        total += x;
    }
    int pos = woff + (scan - c);                 // global exclusive prefix

    // --- scatter kept tokens (consecutive per thread) ---
#pragma unroll
    for (int j = 0; j < 8; ++j) {
        if (keep_hi & (0x80ULL << (8 * j))) {
            orow[pos++] = (int)((xv >> (8 * j)) & 0xffULL);
        }
    }

    // --- tail zero-fill + lens ---
    for (int i = total + tid; i < CTC_T; i += 1024) orow[i] = BLANK;
    if (tid == 0) lens[b] = total;
}

// ---------------------------------------------------------------------------
extern "C" void kernel_launch(void* const* d_in, const int* in_sizes, int n_in,
                              void* d_out, int out_size, void* d_ws, size_t ws_size,
                              hipStream_t stream) {
    const float* emission = (const float*)d_in[0];
    int* out = (int*)d_out;                 // [B*T btokens][B lens], int32
    int* btokens = out;
    int* lens = out + (size_t)CTC_B * CTC_T;

    unsigned char* idx = (unsigned char*)d_ws;   // B*T bytes

    const int total_threads = CTC_B * CTC_T * 8; // 8 lanes per row
    ctc_argmax_kernel<<<total_threads / 256, 256, 0, stream>>>(emission, idx);
    ctc_compact_kernel<<<CTC_B, 1024, 0, stream>>>(idx, btokens, lens);
}

// Round 4
// 21.397 us; speedup vs baseline: 1.9224x; 1.0978x over previous
//
#include <hip/hip_runtime.h>
#include <hip/hip_bf16.h>

// Problem constants (from reference setup_inputs): emission [B, T, V] float32
#define CTC_B 64
#define CTC_T 8192
#define CTC_V 32
#define BLANK 0

// ---------------------------------------------------------------------------
// Kernel 1: argmax over labels. 4 lanes per (b,t) row; each lane loads TWO
// independent float4s (elements [4s,4s+4) and [16+4s,16+4s+4)) -> 2-deep load
// ILP, 16 rows per wave, only 2 shuffle-reduce rounds.
// First-occurrence tie-break: in-lane indices are ascending with strict '>',
// cross-lane reduce prefers the smaller index on exact float equality.
// ---------------------------------------------------------------------------
__global__ __launch_bounds__(256) void ctc_argmax_kernel(
    const float* __restrict__ em, unsigned char* __restrict__ idx) {
    int tid = blockIdx.x * blockDim.x + threadIdx.x;   // 4 threads per row
    int row = tid >> 2;
    int sub = tid & 3;
    const float4* p = reinterpret_cast<const float4*>(em) + (size_t)row * 8 + sub;
    float4 a = p[0];   // covers elements 4*sub   .. 4*sub+3
    float4 b = p[4];   // covers elements 16+4*sub .. 16+4*sub+3
    const int b1 = sub * 4, b2 = 16 + sub * 4;

    float best = a.x; int bi = b1;
    if (a.y > best) { best = a.y; bi = b1 + 1; }
    if (a.z > best) { best = a.z; bi = b1 + 2; }
    if (a.w > best) { best = a.w; bi = b1 + 3; }
    if (b.x > best) { best = b.x; bi = b2;     }
    if (b.y > best) { best = b.y; bi = b2 + 1; }
    if (b.z > best) { best = b.z; bi = b2 + 2; }
    if (b.w > best) { best = b.w; bi = b2 + 3; }

    // reduce across the 4-lane group (xor masks 1,2 stay in-group)
#pragma unroll
    for (int m = 1; m < 4; m <<= 1) {
        float ob = __shfl_xor(best, m, 64);
        int   oi = __shfl_xor(bi,   m, 64);
        if (ob > best || (ob == best && oi < bi)) { best = ob; bi = oi; }
    }
    if (sub == 0) idx[row] = (unsigned char)bi;   // 16 consecutive bytes/wave
}

// ---------------------------------------------------------------------------
// SWAR: high bit of each byte set iff that byte of x is nonzero.
// ---------------------------------------------------------------------------
__device__ __forceinline__ unsigned long long nzmask(unsigned long long x) {
    return (x | ((x & 0x7f7f7f7f7f7f7f7fULL) + 0x7f7f7f7f7f7f7f7fULL))
           & 0x8080808080808080ULL;
}

// ---------------------------------------------------------------------------
// Kernel 2 (fused colkeep + compact): one block of 1024 threads per batch
// row; each thread owns 8 CONSECUTIVE columns (one u64 byte-vector). Single
// pass, single barrier:
//   colkeep: SWAR compare of column t vs t-1 for batch rows 0,1 branchless,
//            rare loop over rows 2..63 only while some byte is undecided.
//   scan:    per-thread popcount -> wave shfl_up scan -> 16-int LDS -> barrier
//   scatter: <=8 consecutive int stores per thread + vectorized tail fill.
// ---------------------------------------------------------------------------
__global__ __launch_bounds__(1024) void ctc_compact_kernel(
    const unsigned char* __restrict__ idx,
    int* __restrict__ btokens, int* __restrict__ lens) {
    const int b   = blockIdx.x;
    const int tid = threadIdx.x;
    const int t8  = tid * 8;                     // first column this thread owns
    const unsigned char* row = idx + (size_t)b * CTC_T;
    int* orow = btokens + (size_t)b * CTC_T;

    __shared__ int s_wsum[16];
    const int lane = tid & 63;
    const int wid  = tid >> 6;

    // --- load own 8 values + boundary byte, and dedup rows 0,1 ---
    const unsigned long long xv = *reinterpret_cast<const unsigned long long*>(row + t8);
    const unsigned char* r0 = idx;               // batch row 0
    const unsigned char* r1 = idx + CTC_T;       // batch row 1
    unsigned long long x0 = *reinterpret_cast<const unsigned long long*>(r0 + t8);
    unsigned long long x1 = *reinterpret_cast<const unsigned long long*>(r1 + t8);
    unsigned char p0 = (t8 == 0) ? (unsigned char)0 : r0[t8 - 1];
    unsigned char p1 = (t8 == 0) ? (unsigned char)0 : r1[t8 - 1];

    // colkeep high-bit mask: byte j <-> column t8+j ; prev column = byte j-1
    unsigned long long hk = nzmask(x0 ^ ((x0 << 8) | (unsigned long long)p0))
                          | nzmask(x1 ^ ((x1 << 8) | (unsigned long long)p1));
    if (t8 == 0) hk |= 0x80ULL;                  // col_keep[0] = 1 always

    unsigned long long und = ~hk & 0x8080808080808080ULL;
    for (int bb = 2; bb < CTC_B && und; ++bb) {
        const unsigned char* rb = idx + (size_t)bb * CTC_T;
        unsigned long long xb = *reinterpret_cast<const unsigned long long*>(rb + t8);
        unsigned char pb = (t8 == 0) ? (unsigned char)0 : rb[t8 - 1];
        hk |= nzmask(xb ^ ((xb << 8) | (unsigned long long)pb));
        und = ~hk & 0x8080808080808080ULL;
    }

    // keep = col_keep & (value != BLANK)   (BLANK==0 -> nonzero byte)
    const unsigned long long keep_hi = hk & nzmask(xv);
    const int c = __popcll(keep_hi);

    // --- block exclusive scan of per-thread counts ---
    int scan = c;
#pragma unroll
    for (int m = 1; m < 64; m <<= 1) {
        int o = __shfl_up(scan, m, 64);
        if (lane >= m) scan += o;
    }
    if (lane == 63) s_wsum[wid] = scan;          // wave total (inclusive of last)
    __syncthreads();

    int woff = 0, total = 0;
#pragma unroll
    for (int w = 0; w < 16; ++w) {
        int x = s_wsum[w];
        if (w < wid) woff += x;
        total += x;
    }
    int pos = woff + (scan - c);                 // global exclusive prefix

    // --- scatter kept tokens (consecutive per thread) ---
#pragma unroll
    for (int j = 0; j < 8; ++j) {
        if (keep_hi & (0x80ULL << (8 * j))) {
            orow[pos++] = (int)((xv >> (8 * j)) & 0xffULL);
        }
    }

    // --- tail zero-fill (int4-vectorized) + lens ---
    int vstart = (total + 3) & ~3;               // 16B-aligned fill start
    if (tid < vstart - total) orow[total + tid] = BLANK;
    int4* vout = reinterpret_cast<int4*>(orow + vstart);
    const int nvec = (CTC_T - vstart) >> 2;
    const int4 z = make_int4(BLANK, BLANK, BLANK, BLANK);
    for (int i = tid; i < nvec; i += 1024) vout[i] = z;
    if (tid == 0) lens[b] = total;
}

// ---------------------------------------------------------------------------
extern "C" void kernel_launch(void* const* d_in, const int* in_sizes, int n_in,
                              void* d_out, int out_size, void* d_ws, size_t ws_size,
                              hipStream_t stream) {
    const float* emission = (const float*)d_in[0];
    int* out = (int*)d_out;                 // [B*T btokens][B lens], int32
    int* btokens = out;
    int* lens = out + (size_t)CTC_B * CTC_T;

    unsigned char* idx = (unsigned char*)d_ws;   // B*T bytes

    const int total_threads = CTC_B * CTC_T * 4; // 4 lanes per row
    ctc_argmax_kernel<<<total_threads / 256, 256, 0, stream>>>(emission, idx);
    ctc_compact_kernel<<<CTC_B, 1024, 0, stream>>>(idx, btokens, lens);
}